// Round 1
// baseline (939.333 us; speedup 1.0000x reference)
//
#include <hip/hip_runtime.h>
#include <hip/hip_bf16.h>
#include <cstdint>
#include <cstddef>

// Problem constants
#define BATCH 4096
#define TT    20     // SEQ_LEN
#define DD    512    // INPUT_SIZE == HIDDEN_SIZE
#define RR    20     // RANK
#define ROWS  16     // batch rows per block  (4096/16 = 256 blocks = 256 CUs)
#define TB    512    // threads per block (8 waves)
#define HPAD  (DD + 8)   // 520: padded LDS stride (16B-aligned, bank-spread)

__device__ __forceinline__ float sigf(float x) {
  return 1.0f / (1.0f + __expf(-x));
}
// NaN-safe fast tanh: 1 - 2/(1+e^{2x}) ; x->+inf: e=inf -> 1 ; x->-inf: e=0 -> -1
__device__ __forceinline__ float tanh_fast(float x) {
  float e = __expf(2.0f * x);
  return 1.0f - 2.0f / (1.0f + e);
}

__global__ __launch_bounds__(TB, 2) void lstm_fused(
    const float* __restrict__ x,      // [B][T][D]
    const float* __restrict__ wih_a,  // [D][R]
    const float* __restrict__ wih_b,  // [R][4D]
    const float* __restrict__ b_ih,   // [4D]
    const float* __restrict__ whh_a,  // [D][R]
    const float* __restrict__ whh_b,  // [R][4D]
    const float* __restrict__ b_hh,   // [4D]
    float* __restrict__ out,          // [B][T][D] ++ h[B][D] ++ c[B][D]
    float* __restrict__ xa)           // scratch [B][T][R]
{
  // LDS: 16*520*4 + 20*520*2 + 40*16*4 = 33.3K + 20.8K + 2.56K = 56.7 KB
  __shared__ __align__(16) float h_lds[ROWS][HPAD];          // f32 hidden state
  __shared__ __align__(16) unsigned short at_lds[RR][HPAD];  // whh_a^T as bf16 bits
  __shared__ __align__(16) float abufT[2 * RR][ROWS];        // [k][row]: xa(0..19) | ha(20..39)

  const int tid  = threadIdx.x;
  const int brow = blockIdx.x * ROWS;

  // ---- P0a: whh_a [D][R] -> at_lds[r][k]  (bf16 RNE) ----
  for (int idx = tid; idx < DD * RR; idx += TB) {
    int k = idx / RR, r = idx - k * RR;
    uint32_t u = __float_as_uint(whh_a[idx]);
    u += 0x7FFFu + ((u >> 16) & 1u);          // round-to-nearest-even
    at_lds[r][k] = (unsigned short)(u >> 16);
  }
  // ---- P0b: zero h ----
  for (int idx = tid; idx < ROWS * HPAD; idx += TB)
    (&h_lds[0][0])[idx] = 0.0f;

  // ---- P0c: xa[b][t][r] = x[b][t][:] . wih_a[:][r]  (f32) ----
  for (int oid = tid; oid < ROWS * TT * RR; oid += TB) {
    int row = oid / (TT * RR);
    int rem = oid - row * (TT * RR);
    int t = rem / RR, r = rem - t * RR;
    const float* xp = x + ((size_t)(brow + row) * TT + t) * DD;
    float acc = 0.0f;
#pragma unroll 2
    for (int k = 0; k < DD; k += 4) {
      float4 xv = *(const float4*)(xp + k);
      acc = fmaf(xv.x, wih_a[(k + 0) * RR + r], acc);
      acc = fmaf(xv.y, wih_a[(k + 1) * RR + r], acc);
      acc = fmaf(xv.z, wih_a[(k + 2) * RR + r], acc);
      acc = fmaf(xv.w, wih_a[(k + 3) * RR + r], acc);
    }
    xa[(size_t)(brow + row) * (TT * RR) + t * RR + r] = acc;
  }

  // ---- persistent per-thread state: thread = hidden unit j = tid ----
  float c_reg[ROWS];
#pragma unroll
  for (int m = 0; m < ROWS; ++m) c_reg[m] = 0.0f;
  float bias[4];
#pragma unroll
  for (int g = 0; g < 4; ++g) bias[g] = b_ih[g * DD + tid] + b_hh[g * DD + tid];

  // step1 mapping (waves 0..4 : tid < 320), hoisted out of the time loop
  const int s1_row = tid / RR;
  const int s1_r   = tid - s1_row * RR;
  const float* wb_ih = wih_b + tid;   // + k*4D + g*D
  const float* wb_hh = whh_b + tid;

  __syncthreads();

  for (int t = 0; t < TT; ++t) {
    // ---------- step1: ha = h @ whh_a -> abufT[20+r][row]; xa copy -> abufT[r][row]
    if (tid < ROWS * RR) {                       // waves 0..4 (clean wave split at 320)
      float acc = 0.0f;
#pragma unroll 2
      for (int k = 0; k < DD; k += 4) {
        float4 hv = *(const float4*)&h_lds[s1_row][k];
        uint2 aw  = *(const uint2*)&at_lds[s1_r][k];
        float a0 = __uint_as_float((aw.x & 0xFFFFu) << 16);
        float a1 = __uint_as_float(aw.x & 0xFFFF0000u);
        float a2 = __uint_as_float((aw.y & 0xFFFFu) << 16);
        float a3 = __uint_as_float(aw.y & 0xFFFF0000u);
        acc = fmaf(hv.x, a0, acc);
        acc = fmaf(hv.y, a1, acc);
        acc = fmaf(hv.z, a2, acc);
        acc = fmaf(hv.w, a3, acc);
      }
      abufT[RR + s1_r][s1_row] = acc;
    } else {                                     // waves 5..7: stage xa for this t
      int idx = tid - ROWS * RR;                 // 0..191
      for (int i = idx; i < ROWS * RR; i += TB - ROWS * RR) {
        int row = i / RR, r = i - row * RR;
        abufT[r][row] = xa[(size_t)(brow + row) * (TT * RR) + t * RR + r];
      }
    }
    __syncthreads();

    // ---------- step2: gates[row][g] = bias + sum_k a[row][k] * B[k][g*D + j]
    float acc[ROWS][4];
#pragma unroll
    for (int m = 0; m < ROWS; ++m)
#pragma unroll
      for (int g = 0; g < 4; ++g) acc[m][g] = bias[g];

#pragma unroll 2
    for (int k = 0; k < RR; ++k) {               // xa part (wih_b)
      float b0 = wb_ih[(size_t)k * (4 * DD) + 0 * DD];
      float b1 = wb_ih[(size_t)k * (4 * DD) + 1 * DD];
      float b2 = wb_ih[(size_t)k * (4 * DD) + 2 * DD];
      float b3 = wb_ih[(size_t)k * (4 * DD) + 3 * DD];
      const float4* ar = (const float4*)abufT[k];
      float4 A0 = ar[0], A1 = ar[1], A2 = ar[2], A3 = ar[3];
      float av[ROWS] = {A0.x, A0.y, A0.z, A0.w, A1.x, A1.y, A1.z, A1.w,
                        A2.x, A2.y, A2.z, A2.w, A3.x, A3.y, A3.z, A3.w};
#pragma unroll
      for (int m = 0; m < ROWS; ++m) {
        float a = av[m];
        acc[m][0] = fmaf(a, b0, acc[m][0]);
        acc[m][1] = fmaf(a, b1, acc[m][1]);
        acc[m][2] = fmaf(a, b2, acc[m][2]);
        acc[m][3] = fmaf(a, b3, acc[m][3]);
      }
    }
#pragma unroll 2
    for (int k = 0; k < RR; ++k) {               // ha part (whh_b)
      float b0 = wb_hh[(size_t)k * (4 * DD) + 0 * DD];
      float b1 = wb_hh[(size_t)k * (4 * DD) + 1 * DD];
      float b2 = wb_hh[(size_t)k * (4 * DD) + 2 * DD];
      float b3 = wb_hh[(size_t)k * (4 * DD) + 3 * DD];
      const float4* ar = (const float4*)abufT[RR + k];
      float4 A0 = ar[0], A1 = ar[1], A2 = ar[2], A3 = ar[3];
      float av[ROWS] = {A0.x, A0.y, A0.z, A0.w, A1.x, A1.y, A1.z, A1.w,
                        A2.x, A2.y, A2.z, A2.w, A3.x, A3.y, A3.z, A3.w};
#pragma unroll
      for (int m = 0; m < ROWS; ++m) {
        float a = av[m];
        acc[m][0] = fmaf(a, b0, acc[m][0]);
        acc[m][1] = fmaf(a, b1, acc[m][1]);
        acc[m][2] = fmaf(a, b2, acc[m][2]);
        acc[m][3] = fmaf(a, b3, acc[m][3]);
      }
    }

    // ---------- step3: cell update + writes ----------
#pragma unroll
    for (int m = 0; m < ROWS; ++m) {
      float iv = sigf(acc[m][0]);
      float fv = sigf(acc[m][1]);
      float gv = tanh_fast(acc[m][2]);
      float ov = sigf(acc[m][3]);
      float c  = fmaf(fv, c_reg[m], iv * gv);
      c_reg[m] = c;
      float h  = ov * tanh_fast(c);
      h_lds[m][tid] = h;
      out[((size_t)(brow + m) * TT + t) * DD + tid] = h;
    }
    __syncthreads();   // h_lds ready for next step1; abufT safe to overwrite
  }

  // ---- final (h, c) ----
  float* out_h = out + (size_t)BATCH * TT * DD;
  float* out_c = out_h + (size_t)BATCH * DD;
#pragma unroll
  for (int m = 0; m < ROWS; ++m) {
    out_h[(size_t)(brow + m) * DD + tid] = h_lds[m][tid];
    out_c[(size_t)(brow + m) * DD + tid] = c_reg[m];
  }
}

extern "C" void kernel_launch(void* const* d_in, const int* in_sizes, int n_in,
                              void* d_out, int out_size, void* d_ws, size_t ws_size,
                              hipStream_t stream) {
  const float* x      = (const float*)d_in[0];
  const float* wih_a  = (const float*)d_in[1];
  const float* wih_b  = (const float*)d_in[2];
  const float* b_ih   = (const float*)d_in[3];
  const float* whh_a  = (const float*)d_in[4];
  const float* whh_b  = (const float*)d_in[5];
  const float* b_hh   = (const float*)d_in[6];
  float* out = (float*)d_out;

  // xa scratch: [B][T][R] f32 = 6.55 MB. Prefer d_ws; else borrow the final-h
  // region of d_out (8.39 MB) — it is only overwritten after all xa reads,
  // and each block touches only its own rows in both regions.
  const size_t xa_bytes = (size_t)BATCH * TT * RR * sizeof(float);
  float* xa = (ws_size >= xa_bytes) ? (float*)d_ws
                                    : out + (size_t)BATCH * TT * DD;

  dim3 grid(BATCH / ROWS);   // 256
  dim3 block(TB);            // 512
  hipLaunchKernelGGL(lstm_fused, grid, block, 0, stream,
                     x, wih_a, wih_b, b_ih, whh_a, whh_b, b_hh, out, xa);
}